// Round 6
// baseline (303.862 us; speedup 1.0000x reference)
//
#include <hip/hip_runtime.h>
#include <hip/hip_bf16.h>

#define BATCH 32
#define WDIM 512
#define HDIM 512
#define CDIM 3
#define KPSF 32
#define NPRED (BATCH*WDIM*HDIM*CDIM)  // 25165824

#define TW 88        // tile width  (x): 64 + 15 + 9 pad -> 8-elem aligned rows
#define TH 63        // tile height (y): 32 + 31
#define TE (TW*TH)   // 5544 per channel
#define TALL (TW*TH*CDIM)  // 16632 dense elements

typedef __bf16 bf16x8 __attribute__((ext_vector_type(8)));
typedef float floatx16 __attribute__((ext_vector_type(16)));
typedef float fx4 __attribute__((ext_vector_type(4)));   // clang vector: ok for nontemporal builtins

// Workgroup barrier that does NOT drain vmcnt: only LDS ordering is required
// between rounds; global loads/stores stay in flight across rounds/groups.
__device__ __forceinline__ void barrier_lgkm() {
    __asm__ volatile("s_waitcnt lgkmcnt(0)\n\ts_barrier" ::: "memory");
}

// Pack psf[b,i,j,0,c] (fp32) into MFMA A-fragment order (bf16):
// dst[((c*32 + j)*2 + h)*64 + lane][t] = psf[b=lane&31][i=16h+8*(lane>>5)+t][j][c]
__global__ __launch_bounds__(64) void pack_psf(const float* __restrict__ psf,
                                               __bf16* __restrict__ dst,
                                               float* __restrict__ loss) {
    if (blockIdx.x == 0 && threadIdx.x == 0) *loss = 0.f;
    int idx = blockIdx.x;              // [0,192) = ((c*32 + j)*2 + h)
    int h = idx & 1;
    int j = (idx >> 1) & 31;
    int c = idx >> 6;
    int lane = threadIdx.x;
    int b = lane & 31;
    int q = lane >> 5;
    bf16x8 v;
#pragma unroll
    for (int t = 0; t < 8; ++t) {
        int i = 16*h + 8*q + t;
        v[t] = (__bf16)psf[((size_t)(b*KPSF + i)*KPSF + j)*CDIM + c];
    }
    *(bf16x8*)(dst + (size_t)(idx*64 + lane)*8) = v;
}

// Block = 192 threads = 3 waves; wave w = channel c of the same
// (x-set of 8 x's at stride 8, y-tile of 32). MFMA m=batch, n=y, k=i-taps.
// K-loop split into 2 s-groups of 4 so group g's stores/obs stream under
// group g+1's compute (vmcnt never drained).
__global__ __launch_bounds__(192, 3) void conv_mfma(
    const float* __restrict__ obs,    // [B,W,H,C]
    const float* __restrict__ img,    // [W,H,C]
    const __bf16* __restrict__ psfA,  // packed A-frags
    float* __restrict__ out)          // [B,W,H,C] pred, then loss scalar
{
    __shared__ __align__(16) __bf16 sImg[CDIM][TE];   // 33264 B, live throughout
    __shared__ __align__(16) float sOut[32*32*3];     // 12288 B transpose staging

    const int tid  = threadIdx.x;
    const int lane = tid & 63;
    const int c    = tid >> 6;      // wave index = channel
    const int n    = lane & 31;     // MFMA n (y within tile)
    const int q    = lane >> 5;     // k-half selector

    const int bx = blockIdx.x;      // [0,1024)
    const int r8 = bx & 7;          // x mod-8 class
    const int g  = (bx >> 3) & 7;   // 64-wide x group
    const int yt = bx >> 6;         // y tile [0,16)
    const int x0 = g*64 + r8;       // block's x's = x0 + 8s, s=0..7
    const int ytile = yt*32;
    const int g0 = bx & 1;          // group-order swizzle: desync co-resident blocks

    // ---- stage transposed image tile ----
    const bool interior = (x0 >= 15) && (x0 <= WDIM - 73) &&
                          (ytile >= 15) && (ytile <= HDIM - 48);
    if (interior) {
        const int col0 = (ytile - 15)*3;           // >= 0
        const int p2 = col0 & 3;
        const float* gb = img + (size_t)(x0 - 15)*(HDIM*CDIM) + (col0 - p2);
#pragma unroll 2
        for (int f = tid; f < 88*48; f += 192) {
            int r = f / 48;                        // x-row 0..87
            int v = f - r*48;                      // float4 slot 0..47
            fx4 val = *(const fx4*)(gb + (size_t)r*(HDIM*CDIM) + 4*v);
            int d = 4*v - p2;                      // col offset of val[0], in [-3,189)
#pragma unroll
            for (int u = 0; u < 4; ++u) {
                int dd = d + u;
                if (dd >= 0 && dd < 189) {
                    int yl = (dd*171) >> 9;        // dd/3 for dd<511
                    int cc = dd - 3*yl;
                    sImg[cc][yl*TW + r] = (__bf16)val[u];
                }
            }
        }
    } else {
#pragma unroll 4
        for (int e = tid; e < TALL; e += 192) {
            int xl = e / (TH*CDIM);
            int rr = e - xl*(TH*CDIM);
            int yl = rr / 3;
            int cc = rr - yl*3;
            int xg = x0 + xl - 15;
            int yg = ytile + yl - 15;
            float v = 0.f;
            if ((unsigned)xg < WDIM && (unsigned)yg < HDIM)
                v = img[((size_t)xg*HDIM + yg)*CDIM + cc];
            sImg[cc][yl*TW + xl] = (__bf16)v;
        }
    }
    __syncthreads();

    const __bf16* pA = psfA + (size_t)c*(KPSF*2*64*8) + (size_t)lane*8;
    const __bf16* sI = (const __bf16*)&sImg[c][q*8];

    // epilogue addressing (96-float contiguous runs, 64B-aligned)
    float ls = 0.f;
    size_t base[4];
#pragma unroll
    for (int k = 0; k < 4; ++k) {
        int f = tid + 192*k;                    // float4 index [0,768)
        int fb = f / 24;                        // batch
        int rem = (f - fb*24) * 4;              // offset in 96-float run
        base[k] = (((size_t)fb*WDIM + x0)*HDIM + ytile)*CDIM + rem;
    }
    // round t (execution order) -> s index
    // p = t>>2 (group position), grp = p ^ g0, s = 4*grp + (t&3)
    fx4 obA[4], obB[4];
#pragma unroll
    for (int k = 0; k < 4; ++k)
        obA[k] = __builtin_nontemporal_load(
            (const fx4*)&obs[base[k] + (size_t)(4*g0 + 0)*12288]);
#pragma unroll
    for (int k = 0; k < 4; ++k)
        obB[k] = __builtin_nontemporal_load(
            (const fx4*)&obs[base[k] + (size_t)(4*g0 + 1)*12288]);

#pragma unroll 1
    for (int p = 0; p < 2; ++p) {
        const int grp = p ^ g0;
        const int s0  = 4*grp;

        // ---- group j-loop: 6 LDS b128 + 8 MFMA per j ----
        floatx16 acc[4] = {};
        const __bf16* sIs = sI + s0*8;
#pragma unroll 4
        for (int j = 0; j < 32; ++j) {
            bf16x8 A0 = *(const bf16x8*)(pA + (size_t)j*1024);
            bf16x8 A1 = *(const bf16x8*)(pA + (size_t)j*1024 + 512);
            const __bf16* rowp = sIs + (n + j)*TW;
            bf16x8 C[6];
#pragma unroll
            for (int rr = 0; rr < 6; ++rr)
                C[rr] = *(const bf16x8*)(rowp + rr*8);   // 16B-aligned ds_read_b128
#pragma unroll
            for (int ss = 0; ss < 4; ++ss) {
                acc[ss] = __builtin_amdgcn_mfma_f32_32x32x16_bf16(A0, C[ss],   acc[ss], 0, 0, 0);
                acc[ss] = __builtin_amdgcn_mfma_f32_32x32x16_bf16(A1, C[ss+2], acc[ss], 0, 0, 0);
            }
        }

        // ---- group epilogue: 4 transpose rounds, lgkm-only barriers ----
#pragma unroll 1
        for (int k = 0; k < 4; ++k) {
            const int s = s0 + k;
            const int t = 4*p + k;
            barrier_lgkm();    // prior round's sOut reads complete (LDS only)
#pragma unroll
            for (int rr = 0; rr < 16; ++rr) {
                int b = (rr & 3) + 8*(rr >> 2) + 4*q;   // D row = batch
                sOut[(b*32 + n)*3 + c] = acc[k][rr];    // bank 3n+c: conflict-free
            }
            barrier_lgkm();    // sOut writes visible (LDS only)
            fx4 cur[4];
#pragma unroll
            for (int kk = 0; kk < 4; ++kk) { cur[kk] = obA[kk]; obA[kk] = obB[kk]; }
            if (t <= 5) {      // prefetch round t+2's obs (possibly across groups)
                const int tn = t + 2;
                const int sn = 4*((tn >> 2) ^ g0) + (tn & 3);
#pragma unroll
                for (int kk = 0; kk < 4; ++kk)
                    obB[kk] = __builtin_nontemporal_load(
                        (const fx4*)&obs[base[kk] + (size_t)sn*12288]);
            }
#pragma unroll
            for (int kk = 0; kk < 4; ++kk) {
                fx4 pv = *(const fx4*)&sOut[4*(tid + 192*kk)];
                __builtin_nontemporal_store(pv,
                    (fx4*)&out[base[kk] + (size_t)s*12288]);
                fx4 d = cur[kk] - pv;
                ls += d[0]*d[0] + d[1]*d[1] + d[2]*d[2] + d[3]*d[3];
            }
        }
    }

#pragma unroll
    for (int m = 32; m >= 1; m >>= 1) ls += __shfl_xor(ls, m, 64);
    if (lane == 0) atomicAdd(out + NPRED, ls * (1.0f/(float)NPRED));
}

extern "C" void kernel_launch(void* const* d_in, const int* in_sizes, int n_in,
                              void* d_out, int out_size, void* d_ws, size_t ws_size,
                              hipStream_t stream) {
    const float* obs = (const float*)d_in[0];   // observed_images [32,512,512,3]
    const float* img = (const float*)d_in[1];   // estimated_image [512,512,3]
    const float* psf = (const float*)d_in[2];   // psfs [32,32,32,1,3]
    float* out = (float*)d_out;                 // pred (25165824) + loss (1)
    __bf16* psfA = (__bf16*)d_ws;               // 196608 B packed psf frags

    pack_psf<<<192, 64, 0, stream>>>(psf, psfA, out + NPRED);
    conv_mfma<<<1024, 192, 0, stream>>>(obs, img, psfA, out);
}